// Round 4
// baseline (1082.118 us; speedup 1.0000x reference)
//
#include <hip/hip_runtime.h>
#include <hip/hip_bf16.h>
#include <math.h>

#define B_    4
#define CIN_  256
#define COUT_ 256
#define H_    128
#define W_    128
#define HW_   16384
#define SD_   512
#define HO_   130
#define HU_   260
#define NT_   12

typedef unsigned short ushort_t;
typedef __attribute__((ext_vector_type(8))) short short8;
typedef __attribute__((ext_vector_type(4))) short short4v;
typedef __attribute__((ext_vector_type(4))) float f32x4;

__device__ inline ushort_t f2bf_(float v) {
  union { float f; unsigned u; } x; x.f = v;
  unsigned r = x.u + 0x7fffu + ((x.u >> 16) & 1u);
  return (ushort_t)(r >> 16);
}
__device__ inline float bf2f_(ushort_t h) {
  union { unsigned u; float f; } x; x.u = ((unsigned)h) << 16;
  return x.f;
}

// ---------------- K1: modulation s[b][cin] ----------------
__global__ __launch_bounds__(256) void k_mod(const float* __restrict__ style,
                                             const float* __restrict__ mw,
                                             const float* __restrict__ mb,
                                             float* __restrict__ s) {
  int wid  = (blockIdx.x * blockDim.x + threadIdx.x) >> 6;
  int lane = threadIdx.x & 63;
  int b = wid >> 8, ci = wid & 255;
  const float* st = style + b * SD_;
  const float* w  = mw + ci * SD_;
  float acc = 0.f;
  for (int k = lane; k < SD_; k += 64) acc += st[k] * w[k];
  for (int off = 32; off; off >>= 1) acc += __shfl_down(acc, off);
  if (lane == 0) s[wid] = acc * 0.044194173824159216f + mb[ci];
}

// ---------------- K2: demod[b][cout] ----------------
__global__ __launch_bounds__(256) void k_demod(const float* __restrict__ weight,
                                               const float* __restrict__ s,
                                               float* __restrict__ demod) {
  int wid  = (blockIdx.x * blockDim.x + threadIdx.x) >> 6;
  int lane = threadIdx.x & 63;
  int b = wid >> 8, co = wid & 255;
  const float* wrow = weight + co * CIN_ * 9;
  const float* sb   = s + b * CIN_;
  float acc = 0.f;
  for (int e = lane; e < CIN_ * 9; e += 64) {
    float p = wrow[e] * sb[e / 9];
    acc += p * p;
  }
  for (int off = 32; off; off >>= 1) acc += __shfl_down(acc, off);
  if (lane == 0) demod[wid] = rsqrtf(acc + 1e-8f);
}

// ---------------- K2b: weight pre-transform to MFMA fragment layout ----------------
// layout: [tap(9)][cb(2)][kb(8)][kc(4)][co_row(128)][j(8)]   (hi / lo arrays)
__global__ __launch_bounds__(256) void k_prep_w(const float* __restrict__ W,
                                                ushort_t* __restrict__ Wth,
                                                ushort_t* __restrict__ Wtl) {
  int idx = blockIdx.x * 256 + threadIdx.x;
  if (idx >= 589824) return;
  int j  = idx & 7;
  int co = (idx >> 3) & 127;
  int kc = (idx >> 10) & 3;
  int kb = (idx >> 12) & 7;
  int cb = (idx >> 15) & 1;
  int t  = idx >> 16;
  int ci  = kb * 32 + kc * 8 + j;
  int cog = cb * 128 + co;
  float v = W[(cog * CIN_ + ci) * 9 + t];
  ushort_t h = f2bf_(v);
  Wth[idx] = h;
  Wtl[idx] = f2bf_(v - bf2f_(h));
}

// ---------------- K3: modulated conv via MFMA (bf16 split-3) ----------------
// block tile: 128 co x (10y x 16x); 4 waves = 4 co-quarters (32co each, am=2, bn=10).
// W fragments direct from L2; X single-buffered in LDS, next chunk reg-staged early.
#define CPL 218                 // LDS cell-plane stride (216 cells + 2 pad)
#define NU  1728                // staging units: 2 jq * 4 kc * 12 hy * 18 hx / ... = 2*864

__global__ __launch_bounds__(256, 2) void k_conv_mfma(
    const float* __restrict__ input, const ushort_t* __restrict__ Wth,
    const ushort_t* __restrict__ Wtl, const float* __restrict__ s,
    const float* __restrict__ demod, const float* __restrict__ bias,
    float* __restrict__ out1) {
  const int tid = threadIdx.x;
  const int b   = blockIdx.z >> 1, cb = blockIdx.z & 1;
  const int y0  = blockIdx.y * 10, x0 = blockIdx.x * 16;
  const int lane = tid & 63, lr = lane & 15, kcc = lane >> 4;
  const int w = tid >> 6;                     // co quarter 0..3

  // X LDS: [kc(4)][hy(12)][hx(18)][j(8)] ushort, plane stride CPL cells
  __shared__ __align__(16) ushort_t XhL[4 * CPL * 8];
  __shared__ __align__(16) ushort_t XlL[4 * CPL * 8];
  __shared__ float sSh[256];

  f32x4 acc[2][10];
#pragma unroll
  for (int i = 0; i < 2; ++i)
#pragma unroll
    for (int jj = 0; jj < 10; ++jj) acc[i][jj] = (f32x4)0.f;

  sSh[tid] = s[b * 256 + tid];
  const float* inb = input + b * 256 * HW_;

  auto xload = [&](int kb, float (&xq)[7][4]) {
#pragma unroll
    for (int k = 0; k < 7; ++k) {
      int u = tid + k * 256;
      if (u < NU) {
        int jq = (u >= 864) ? 1 : 0;
        int cell = u - jq * 864;
        int kc = cell / 216, rem = cell - kc * 216;
        int hy = rem / 18, hx = rem - hy * 18;
        int iy = y0 + hy - 2, ix = x0 + hx - 2;
        bool ok = (unsigned)iy < (unsigned)H_ && (unsigned)ix < (unsigned)W_;
        const float* p = inb + (kb * 32 + kc * 8 + jq * 4) * HW_ + iy * W_ + ix;
#pragma unroll
        for (int u2 = 0; u2 < 4; ++u2) xq[k][u2] = ok ? p[u2 * HW_] : 0.f;
      }
    }
  };
  auto xstore = [&](int kb, float (&xq)[7][4]) {
#pragma unroll
    for (int k = 0; k < 7; ++k) {
      int u = tid + k * 256;
      if (u < NU) {
        int jq = (u >= 864) ? 1 : 0;
        int cell = u - jq * 864;
        int kc = cell / 216, rem = cell - kc * 216;
        int sbase = kb * 32 + kc * 8 + jq * 4;
        ushort_t h[4], l[4];
#pragma unroll
        for (int u2 = 0; u2 < 4; ++u2) {
          float v = xq[k][u2] * sSh[sbase + u2];
          ushort_t hh = f2bf_(v);
          h[u2] = hh;
          l[u2] = f2bf_(v - bf2f_(hh));
        }
        int off = (kc * CPL + rem) * 8 + jq * 4;
        *(short4v*)&XhL[off] = (short4v){(short)h[0], (short)h[1], (short)h[2], (short)h[3]};
        *(short4v*)&XlL[off] = (short4v){(short)l[0], (short)l[1], (short)l[2], (short)l[3]};
      }
    }
  };

  {
    float xq[7][4];
    xload(0, xq);
    __syncthreads();          // sSh visible
    xstore(0, xq);
  }
  __syncthreads();

  const int abase = cb * 32768 + kcc * 1024 + (w * 32 + lr) * 8;

  for (int kb = 0; kb < 8; ++kb) {
    float xn[7][4];
    if (kb < 7) xload(kb + 1, xn);   // issue early — HBM latency hides under MFMAs

    const int kbase = abase + kb * 4096;
#pragma unroll
    for (int ky = 0; ky < 3; ++ky) {
#pragma unroll
      for (int kx = 0; kx < 3; ++kx) {
        const int t = ky * 3 + kx;
        const ushort_t* wh = Wth + kbase + t * 65536;
        const ushort_t* wl = Wtl + kbase + t * 65536;
        short8 ah0 = *(const short8*)(wh);
        short8 ah1 = *(const short8*)(wh + 128);
        short8 al0 = *(const short8*)(wl);
        short8 al1 = *(const short8*)(wl + 128);
#pragma unroll
        for (int bn = 0; bn < 10; ++bn) {
          int c8 = (kcc * CPL + (bn + ky) * 18 + (lr + kx)) * 8;
          short8 bh = *(const short8*)&XhL[c8];
          short8 bl = *(const short8*)&XlL[c8];
          acc[0][bn] = __builtin_amdgcn_mfma_f32_16x16x32_bf16(ah0, bh, acc[0][bn], 0, 0, 0);
          acc[0][bn] = __builtin_amdgcn_mfma_f32_16x16x32_bf16(ah0, bl, acc[0][bn], 0, 0, 0);
          acc[0][bn] = __builtin_amdgcn_mfma_f32_16x16x32_bf16(al0, bh, acc[0][bn], 0, 0, 0);
          acc[1][bn] = __builtin_amdgcn_mfma_f32_16x16x32_bf16(ah1, bh, acc[1][bn], 0, 0, 0);
          acc[1][bn] = __builtin_amdgcn_mfma_f32_16x16x32_bf16(ah1, bl, acc[1][bn], 0, 0, 0);
          acc[1][bn] = __builtin_amdgcn_mfma_f32_16x16x32_bf16(al1, bh, acc[1][bn], 0, 0, 0);
        }
      }
    }
    if (kb < 7) {
      __syncthreads();          // all waves done reading X(kb)
      xstore(kb + 1, xn);
      __syncthreads();          // X(kb+1) visible
    }
  }

  // epilogue: * demod + bias, bounded store (oy always < 130 since 13*10=130)
#pragma unroll
  for (int am = 0; am < 2; ++am) {
#pragma unroll
    for (int r = 0; r < 4; ++r) {
      int cog = cb * 128 + w * 32 + am * 16 + kcc * 4 + r;
      float dm = demod[b * 256 + cog];
      float bv = bias[cog];
      int ox = x0 + lr;
      if (ox < HO_) {
#pragma unroll
        for (int bn = 0; bn < 10; ++bn) {
          int oy = y0 + bn;
          out1[((b * 256 + cog) * HO_ + oy) * HO_ + ox] = acc[am][bn][r] * dm + bv;
        }
      }
    }
  }
}

// ---------------- K4: fused FIR up(2x) -> lrelu -> FIR down(2x) ----------------
#define TS 26
#define XR 36
#define UR 62

__global__ __launch_bounds__(256) void k_fir(const float* __restrict__ src,
                                             const float* __restrict__ upf,
                                             const float* __restrict__ dnf,
                                             float* __restrict__ dst) {
  int plane = blockIdx.z;
  int y0 = blockIdx.y * TS, x0 = blockIdx.x * TS;
  int tid = threadIdx.x;

  __shared__ float buf1[UR * 63];
  __shared__ float buf2[UR * 37];
  __shared__ float fu[NT_], fd[NT_];
  if (tid < NT_) { fu[tid] = upf[tid] * 2.f; fd[tid] = dnf[tid]; }

  const float* sp = src + (size_t)plane * HO_ * HO_;
  for (int idx = tid; idx < XR * XR; idx += 256) {
    int r = idx / XR, c = idx % XR;
    int gy = y0 - 5 + r, gx = x0 - 5 + c;
    float v = 0.f;
    if (gy >= 0 && gy < HO_ && gx >= 0 && gx < HO_) v = sp[gy * HO_ + gx];
    buf1[r * 37 + c] = v;
  }
  __syncthreads();

  for (int idx = tid; idx < UR * XR; idx += 256) {
    int u = idx / XR, c = idx % XR;
    int ug = 2 * y0 - 5 + u;
    float a = 0.f;
    if (ug >= 0 && ug < HU_) {
      int base, toff;
      if (ug & 1) { base = (ug - 5) >> 1; toff = 1; }
      else        { base = (ug >> 1) - 3; toff = 0; }
      int lr2 = base - (y0 - 5);
#pragma unroll
      for (int j = 0; j < 6; ++j) a += fu[2 * j + toff] * buf1[(lr2 + j) * 37 + c];
    }
    buf2[u * 37 + c] = a;
  }
  __syncthreads();

  for (int idx = tid; idx < UR * UR; idx += 256) {
    int u = idx / UR, v = idx % UR;
    int ug = 2 * y0 - 5 + u;
    int vg = 2 * x0 - 5 + v;
    float a = 0.f;
    if (ug >= 0 && ug < HU_ && vg >= 0 && vg < HU_) {
      int base, toff;
      if (vg & 1) { base = (vg - 5) >> 1; toff = 1; }
      else        { base = (vg >> 1) - 3; toff = 0; }
      int lc = base - (x0 - 5);
#pragma unroll
      for (int j = 0; j < 6; ++j) a += fu[2 * j + toff] * buf2[u * 37 + lc + j];
      a = (a >= 0.f ? a : 0.2f * a) * 1.41421356237309515f;
      a = fminf(fmaxf(a, -256.f), 256.f);
    }
    buf1[u * 63 + v] = a;
  }
  __syncthreads();

  for (int idx = tid; idx < TS * UR; idx += 256) {
    int y = idx / UR, v = idx % UR;
    float a = 0.f;
#pragma unroll
    for (int t = 0; t < NT_; ++t) a += fd[t] * buf1[(2 * y + t) * 63 + v];
    buf2[y * 63 + v] = a;
  }
  __syncthreads();

  float* dp = dst + (size_t)plane * HO_ * HO_;
  for (int idx = tid; idx < TS * TS; idx += 256) {
    int y = idx / TS, x = idx % TS;
    float a = 0.f;
#pragma unroll
    for (int t = 0; t < NT_; ++t) a += fd[t] * buf2[y * 63 + 2 * x + t];
    dp[(y0 + y) * HO_ + (x0 + x)] = a;
  }
}

// ---------------- launch ----------------
extern "C" void kernel_launch(void* const* d_in, const int* in_sizes, int n_in,
                              void* d_out, int out_size, void* d_ws, size_t ws_size,
                              hipStream_t stream) {
  (void)in_sizes; (void)n_in; (void)out_size; (void)ws_size;
  const float* input  = (const float*)d_in[0];
  const float* style  = (const float*)d_in[1];
  const float* weight = (const float*)d_in[2];
  const float* mw     = (const float*)d_in[3];
  const float* mb     = (const float*)d_in[4];
  const float* bias   = (const float*)d_in[5];
  const float* upf    = (const float*)d_in[6];
  const float* dnf    = (const float*)d_in[7];
  float* out = (float*)d_out;

  float* out1   = (float*)d_ws;                               // [4][256][130][130]
  float* s      = out1 + (size_t)B_ * COUT_ * HO_ * HO_;      // [4][256]
  float* demod  = s + B_ * CIN_;                              // [4][256]
  ushort_t* Wth = (ushort_t*)(demod + B_ * COUT_);            // 589824
  ushort_t* Wtl = Wth + 589824;                               // 589824

  k_mod   <<<256, 256, 0, stream>>>(style, mw, mb, s);
  k_demod <<<256, 256, 0, stream>>>(weight, s, demod);
  k_prep_w<<<2304, 256, 0, stream>>>(weight, Wth, Wtl);
  k_conv_mfma<<<dim3(9, 13, 8), 256, 0, stream>>>(input, Wth, Wtl, s, demod, bias, out1);
  k_fir   <<<dim3(5, 5, B_ * COUT_), 256, 0, stream>>>(out1, upf, dnf, out);
}

// Round 5
// 482.573 us; speedup vs baseline: 2.2424x; 2.2424x over previous
//
#include <hip/hip_runtime.h>
#include <hip/hip_bf16.h>
#include <math.h>

#define B_    4
#define CIN_  256
#define COUT_ 256
#define H_    128
#define W_    128
#define HW_   16384
#define SD_   512
#define HO_   130
#define HU_   260
#define NT_   12

typedef unsigned short ushort_t;
typedef __attribute__((ext_vector_type(8))) short short8;
typedef __attribute__((ext_vector_type(4))) float f32x4;

__device__ inline ushort_t f2bf_(float v) {
  union { float f; unsigned u; } x; x.f = v;
  unsigned r = x.u + 0x7fffu + ((x.u >> 16) & 1u);
  return (ushort_t)(r >> 16);
}
__device__ inline float bf2f_(ushort_t h) {
  union { unsigned u; float f; } x; x.u = ((unsigned)h) << 16;
  return x.f;
}
__device__ inline void gll16(const ushort_t* g, ushort_t* l) {
  __builtin_amdgcn_global_load_lds(
      (const __attribute__((address_space(1))) unsigned int*)g,
      (__attribute__((address_space(3))) unsigned int*)l, 16, 0, 0);
}

// ---------------- K1: modulation s[b][cin] ----------------
__global__ __launch_bounds__(256) void k_mod(const float* __restrict__ style,
                                             const float* __restrict__ mw,
                                             const float* __restrict__ mb,
                                             float* __restrict__ s) {
  int wid  = (blockIdx.x * blockDim.x + threadIdx.x) >> 6;
  int lane = threadIdx.x & 63;
  int b = wid >> 8, ci = wid & 255;
  const float* st = style + b * SD_;
  const float* w  = mw + ci * SD_;
  float acc = 0.f;
  for (int k = lane; k < SD_; k += 64) acc += st[k] * w[k];
  for (int off = 32; off; off >>= 1) acc += __shfl_down(acc, off);
  if (lane == 0) s[wid] = acc * 0.044194173824159216f + mb[ci];
}

// ---------------- K2: demod[b][cout] ----------------
__global__ __launch_bounds__(256) void k_demod(const float* __restrict__ weight,
                                               const float* __restrict__ s,
                                               float* __restrict__ demod) {
  int wid  = (blockIdx.x * blockDim.x + threadIdx.x) >> 6;
  int lane = threadIdx.x & 63;
  int b = wid >> 8, co = wid & 255;
  const float* wrow = weight + co * CIN_ * 9;
  const float* sb   = s + b * CIN_;
  float acc = 0.f;
  for (int e = lane; e < CIN_ * 9; e += 64) {
    float p = wrow[e] * sb[e / 9];
    acc += p * p;
  }
  for (int off = 32; off; off >>= 1) acc += __shfl_down(acc, off);
  if (lane == 0) demod[wid] = rsqrtf(acc + 1e-8f);
}

// ---------------- K2b: weight pre-transform to MFMA fragment layout ----------------
// layout: [tap(9)][cb(2)][kb(8)][kc(4)][co_row(128)][j(8)]   (hi / lo arrays)
__global__ __launch_bounds__(256) void k_prep_w(const float* __restrict__ W,
                                                ushort_t* __restrict__ Wth,
                                                ushort_t* __restrict__ Wtl) {
  int idx = blockIdx.x * 256 + threadIdx.x;
  if (idx >= 589824) return;
  int j  = idx & 7;
  int co = (idx >> 3) & 127;
  int kc = (idx >> 10) & 3;
  int kb = (idx >> 12) & 7;
  int cb = (idx >> 15) & 1;
  int t  = idx >> 16;
  int ci  = kb * 32 + kc * 8 + j;
  int cog = cb * 128 + co;
  float v = W[(cog * CIN_ + ci) * 9 + t];
  ushort_t h = f2bf_(v);
  Wth[idx] = h;
  Wtl[idx] = f2bf_(v - bf2f_(h));
}

// ---------------- K2c: X pre-transform ----------------
// Xt layout: [b(4)][part(2)][py(128)][px(128)][ci(256)] bf16 (part0=hi, part1=lo)
__global__ __launch_bounds__(256) void k_prep_x(const float* __restrict__ input,
                                                const float* __restrict__ s,
                                                ushort_t* __restrict__ Xt,
                                                float* __restrict__ zp) {
  int b = blockIdx.z, cb = blockIdx.y, px0 = blockIdx.x * 64;
  int tid = threadIdx.x;
  __shared__ float T[64 * 131];
  __shared__ float sSh[128];
  if (tid < 128) sSh[tid] = s[b * 256 + cb * 128 + tid];
  if (blockIdx.x == 0 && blockIdx.y == 0 && blockIdx.z == 0 && tid < 4)
    zp[tid] = 0.f;                       // 16B zero page for OOB gll lanes
  __syncthreads();
  const float* inb = input + (size_t)(b * 256 + cb * 128) * HW_ + px0;
#pragma unroll
  for (int r2 = 0; r2 < 32; ++r2) {
    int idx = r2 * 256 + tid;
    int ci = idx >> 6, p = idx & 63;
    T[p * 131 + ci] = inb[(size_t)ci * HW_ + p] * sSh[ci];
  }
  __syncthreads();
  ushort_t* xb = Xt + (size_t)b * 2 * HW_ * 256 + cb * 128;
#pragma unroll
  for (int r2 = 0; r2 < 32; ++r2) {
    int u = r2 * 256 + tid;
    int cp = u & 63, part = (u >> 6) & 1, p = u >> 7;
    float v0 = T[p * 131 + 2 * cp], v1 = T[p * 131 + 2 * cp + 1];
    ushort_t h0 = f2bf_(v0), h1 = f2bf_(v1);
    ushort_t e0, e1;
    if (part == 0) { e0 = h0; e1 = h1; }
    else { e0 = f2bf_(v0 - bf2f_(h0)); e1 = f2bf_(v1 - bf2f_(h1)); }
    unsigned pk = (unsigned)e0 | ((unsigned)e1 << 16);
    *(unsigned*)(xb + ((size_t)part * HW_ + px0 + p) * 256 + cp * 2) = pk;
  }
}

// ---------------- K3: modulated conv via MFMA (bf16 split-3) ----------------
// block: 128co x (10y x 16x); X staged via global_load_lds (dbuf, 1 barrier/kb);
// W fragments direct from L2; B-fragment reused across the 3 ky taps.
#define XCELLS 864           // 4kc * 216 cells (12hy*18hx)
#define XUNITS 1728          // 2 parts * 864
#define XROUNDS 7
#define XBUFU  1792          // padded to 7*256 units

__global__ __launch_bounds__(256, 2) void k_conv_mfma(
    const ushort_t* __restrict__ Xt, const ushort_t* __restrict__ Wth,
    const ushort_t* __restrict__ Wtl, const float* __restrict__ demod,
    const float* __restrict__ bias, const ushort_t* __restrict__ zpg,
    float* __restrict__ out1) {
  const int tid = threadIdx.x;
  const int b = blockIdx.z >> 1, cb = blockIdx.z & 1;
  const int y0 = blockIdx.y * 10, x0 = blockIdx.x * 16;
  const int lane = tid & 63, lr = lane & 15, kcc = lane >> 4;
  const int w = tid >> 6;

  __shared__ __align__(16) ushort_t XL[2][XBUFU * 8];   // 2 x 28 KB

  f32x4 acc[2][10];
#pragma unroll
  for (int i = 0; i < 2; ++i)
#pragma unroll
    for (int jj = 0; jj < 10; ++jj) acc[i][jj] = (f32x4)0.f;

  // precompute per-round gather pointers (kb-independent)
  const ushort_t* gsrc[XROUNDS];
  bool okr[XROUNDS];
#pragma unroll
  for (int r = 0; r < XROUNDS; ++r) {
    int u = r * 256 + tid;
    const ushort_t* p = zpg;
    bool ok = false;
    if (u < XUNITS) {
      int part = (u >= XCELLS) ? 1 : 0;
      int v = u - part * XCELLS;
      int kc = v / 216, cell = v - kc * 216;
      int hy = cell / 18, hx = cell - hy * 18;
      int iy = y0 + hy - 2, ix = x0 + hx - 2;
      if ((unsigned)iy < 128u && (unsigned)ix < 128u) {
        p = Xt + (((size_t)(b * 2 + part) * HW_ + iy * W_ + ix) << 8) + kc * 8;
        ok = true;
      }
    }
    gsrc[r] = p; okr[r] = ok;
  }

  auto stage = [&](int kb, int bufsel) {
    ushort_t* lb = &XL[bufsel][(size_t)tid * 8];
#pragma unroll
    for (int r = 0; r < XROUNDS; ++r) {
      const ushort_t* g = okr[r] ? gsrc[r] + kb * 32 : zpg;
      gll16(g, lb + r * 2048);
    }
  };

  stage(0, 0);
  __syncthreads();                         // drains vmcnt -> buf0 ready

  for (int kb = 0; kb < 8; ++kb) {
    if (kb < 7) stage(kb + 1, (kb & 1) ^ 1);   // async into other buffer
    const ushort_t* Xc = &XL[kb & 1][0];
    const int wbo = cb * 32768 + kb * 4096 + kcc * 1024 + (w * 32 + lr) * 8;
#pragma unroll
    for (int kx = 0; kx < 3; ++kx) {
      short8 ah[3][2], al[3][2];
#pragma unroll
      for (int ky = 0; ky < 3; ++ky) {
        const int t = ky * 3 + kx;
        const ushort_t* wh = Wth + wbo + t * 65536;
        const ushort_t* wl = Wtl + wbo + t * 65536;
        ah[ky][0] = *(const short8*)wh;
        ah[ky][1] = *(const short8*)(wh + 128);
        al[ky][0] = *(const short8*)wl;
        al[ky][1] = *(const short8*)(wl + 128);
      }
#pragma unroll
      for (int r = 0; r < 12; ++r) {
        const int c16 = (kcc * 216 + r * 18 + lr + kx) * 8;
        short8 bh = *(const short8*)&Xc[c16];
        short8 bl = *(const short8*)&Xc[c16 + 6912];
#pragma unroll
        for (int ky = 0; ky < 3; ++ky) {
          const int bn = r - ky;
          if (bn >= 0 && bn < 10) {
            acc[0][bn] = __builtin_amdgcn_mfma_f32_16x16x32_bf16(ah[ky][0], bh, acc[0][bn], 0, 0, 0);
            acc[0][bn] = __builtin_amdgcn_mfma_f32_16x16x32_bf16(ah[ky][0], bl, acc[0][bn], 0, 0, 0);
            acc[0][bn] = __builtin_amdgcn_mfma_f32_16x16x32_bf16(al[ky][0], bh, acc[0][bn], 0, 0, 0);
            acc[1][bn] = __builtin_amdgcn_mfma_f32_16x16x32_bf16(ah[ky][1], bh, acc[1][bn], 0, 0, 0);
            acc[1][bn] = __builtin_amdgcn_mfma_f32_16x16x32_bf16(ah[ky][1], bl, acc[1][bn], 0, 0, 0);
            acc[1][bn] = __builtin_amdgcn_mfma_f32_16x16x32_bf16(al[ky][1], bh, acc[1][bn], 0, 0, 0);
          }
        }
      }
    }
    if (kb < 7) __syncthreads();           // all waves done with buf; next buf ready
  }

  // epilogue: * demod + bias
#pragma unroll
  for (int am = 0; am < 2; ++am) {
#pragma unroll
    for (int r = 0; r < 4; ++r) {
      int cog = cb * 128 + w * 32 + am * 16 + kcc * 4 + r;
      float dm = demod[b * 256 + cog];
      float bv = bias[cog];
      int ox = x0 + lr;
      if (ox < HO_) {
#pragma unroll
        for (int bn = 0; bn < 10; ++bn) {
          int oy = y0 + bn;
          out1[((b * 256 + cog) * HO_ + oy) * HO_ + ox] = acc[am][bn][r] * dm + bv;
        }
      }
    }
  }
}

// ---------------- K4: fused FIR up(2x) -> lrelu -> FIR down(2x) ----------------
#define TS 26
#define XR 36
#define UR 62

__global__ __launch_bounds__(256) void k_fir(const float* __restrict__ src,
                                             const float* __restrict__ upf,
                                             const float* __restrict__ dnf,
                                             float* __restrict__ dst) {
  int plane = blockIdx.z;
  int y0 = blockIdx.y * TS, x0 = blockIdx.x * TS;
  int tid = threadIdx.x;

  __shared__ float buf1[UR * 63];
  __shared__ float buf2[UR * 37];
  __shared__ float fu[NT_], fd[NT_];
  if (tid < NT_) { fu[tid] = upf[tid] * 2.f; fd[tid] = dnf[tid]; }

  const float* sp = src + (size_t)plane * HO_ * HO_;
  for (int idx = tid; idx < XR * XR; idx += 256) {
    int r = idx / XR, c = idx % XR;
    int gy = y0 - 5 + r, gx = x0 - 5 + c;
    float v = 0.f;
    if (gy >= 0 && gy < HO_ && gx >= 0 && gx < HO_) v = sp[gy * HO_ + gx];
    buf1[r * 37 + c] = v;
  }
  __syncthreads();

  for (int idx = tid; idx < UR * XR; idx += 256) {
    int u = idx / XR, c = idx % XR;
    int ug = 2 * y0 - 5 + u;
    float a = 0.f;
    if (ug >= 0 && ug < HU_) {
      int base, toff;
      if (ug & 1) { base = (ug - 5) >> 1; toff = 1; }
      else        { base = (ug >> 1) - 3; toff = 0; }
      int lr2 = base - (y0 - 5);
#pragma unroll
      for (int j = 0; j < 6; ++j) a += fu[2 * j + toff] * buf1[(lr2 + j) * 37 + c];
    }
    buf2[u * 37 + c] = a;
  }
  __syncthreads();

  for (int idx = tid; idx < UR * UR; idx += 256) {
    int u = idx / UR, v = idx % UR;
    int ug = 2 * y0 - 5 + u;
    int vg = 2 * x0 - 5 + v;
    float a = 0.f;
    if (ug >= 0 && ug < HU_ && vg >= 0 && vg < HU_) {
      int base, toff;
      if (vg & 1) { base = (vg - 5) >> 1; toff = 1; }
      else        { base = (vg >> 1) - 3; toff = 0; }
      int lc = base - (x0 - 5);
#pragma unroll
      for (int j = 0; j < 6; ++j) a += fu[2 * j + toff] * buf2[u * 37 + lc + j];
      a = (a >= 0.f ? a : 0.2f * a) * 1.41421356237309515f;
      a = fminf(fmaxf(a, -256.f), 256.f);
    }
    buf1[u * 63 + v] = a;
  }
  __syncthreads();

  for (int idx = tid; idx < TS * UR; idx += 256) {
    int y = idx / UR, v = idx % UR;
    float a = 0.f;
#pragma unroll
    for (int t = 0; t < NT_; ++t) a += fd[t] * buf1[(2 * y + t) * 63 + v];
    buf2[y * 63 + v] = a;
  }
  __syncthreads();

  float* dp = dst + (size_t)plane * HO_ * HO_;
  for (int idx = tid; idx < TS * TS; idx += 256) {
    int y = idx / TS, x = idx % TS;
    float a = 0.f;
#pragma unroll
    for (int t = 0; t < NT_; ++t) a += fd[t] * buf2[y * 63 + 2 * x + t];
    dp[(y0 + y) * HO_ + (x0 + x)] = a;
  }
}

// ---------------- launch ----------------
extern "C" void kernel_launch(void* const* d_in, const int* in_sizes, int n_in,
                              void* d_out, int out_size, void* d_ws, size_t ws_size,
                              hipStream_t stream) {
  (void)in_sizes; (void)n_in; (void)out_size; (void)ws_size;
  const float* input  = (const float*)d_in[0];
  const float* style  = (const float*)d_in[1];
  const float* weight = (const float*)d_in[2];
  const float* mw     = (const float*)d_in[3];
  const float* mb     = (const float*)d_in[4];
  const float* bias   = (const float*)d_in[5];
  const float* upf    = (const float*)d_in[6];
  const float* dnf    = (const float*)d_in[7];
  float* out = (float*)d_out;

  float* out1   = (float*)d_ws;                               // 69.22 MB
  float* s      = out1 + (size_t)B_ * COUT_ * HO_ * HO_;      // [4][256]
  float* demod  = s + B_ * CIN_;                              // [4][256]
  ushort_t* Wth = (ushort_t*)(demod + B_ * COUT_);            // 1.18 MB
  ushort_t* Wtl = Wth + 589824;                               // 1.18 MB
  float*    zp  = (float*)(Wtl + 589824);                     // 16 B zero page
  ushort_t* Xt  = (ushort_t*)(zp + 4);                        // 64 MB

  k_mod   <<<256, 256, 0, stream>>>(style, mw, mb, s);
  k_prep_x<<<dim3(256, 2, B_), 256, 0, stream>>>(input, s, Xt, zp);
  k_demod <<<256, 256, 0, stream>>>(weight, s, demod);
  k_prep_w<<<2304, 256, 0, stream>>>(weight, Wth, Wtl);
  k_conv_mfma<<<dim3(9, 13, 8), 256, 0, stream>>>(Xt, Wth, Wtl, demod, bias,
                                                  (const ushort_t*)zp, out1);
  k_fir   <<<dim3(5, 5, B_ * COUT_), 256, 0, stream>>>(out1, upf, dnf, out);
}

// Round 6
// 462.539 us; speedup vs baseline: 2.3395x; 1.0433x over previous
//
#include <hip/hip_runtime.h>
#include <hip/hip_bf16.h>
#include <math.h>

#define B_    4
#define CIN_  256
#define COUT_ 256
#define H_    128
#define W_    128
#define HW_   16384
#define SD_   512
#define HO_   130
#define HU_   260
#define NT_   12

typedef unsigned short ushort_t;
typedef __attribute__((ext_vector_type(8))) short short8;
typedef __attribute__((ext_vector_type(4))) float f32x4;

__device__ inline ushort_t f2bf_(float v) {
  union { float f; unsigned u; } x; x.f = v;
  unsigned r = x.u + 0x7fffu + ((x.u >> 16) & 1u);
  return (ushort_t)(r >> 16);
}
__device__ inline float bf2f_(ushort_t h) {
  union { unsigned u; float f; } x; x.u = ((unsigned)h) << 16;
  return x.f;
}
__device__ inline void gll16(const ushort_t* g, ushort_t* l) {
  __builtin_amdgcn_global_load_lds(
      (const __attribute__((address_space(1))) unsigned int*)g,
      (__attribute__((address_space(3))) unsigned int*)l, 16, 0, 0);
}

// ---------------- K1: modulation s[b][cin] ----------------
__global__ __launch_bounds__(256) void k_mod(const float* __restrict__ style,
                                             const float* __restrict__ mw,
                                             const float* __restrict__ mb,
                                             float* __restrict__ s) {
  int wid  = (blockIdx.x * blockDim.x + threadIdx.x) >> 6;
  int lane = threadIdx.x & 63;
  int b = wid >> 8, ci = wid & 255;
  const float* st = style + b * SD_;
  const float* w  = mw + ci * SD_;
  float acc = 0.f;
  for (int k = lane; k < SD_; k += 64) acc += st[k] * w[k];
  for (int off = 32; off; off >>= 1) acc += __shfl_down(acc, off);
  if (lane == 0) s[wid] = acc * 0.044194173824159216f + mb[ci];
}

// ---------------- K2: demod[b][cout] ----------------
__global__ __launch_bounds__(256) void k_demod(const float* __restrict__ weight,
                                               const float* __restrict__ s,
                                               float* __restrict__ demod) {
  int wid  = (blockIdx.x * blockDim.x + threadIdx.x) >> 6;
  int lane = threadIdx.x & 63;
  int b = wid >> 8, co = wid & 255;
  const float* wrow = weight + co * CIN_ * 9;
  const float* sb   = s + b * CIN_;
  float acc = 0.f;
  for (int e = lane; e < CIN_ * 9; e += 64) {
    float p = wrow[e] * sb[e / 9];
    acc += p * p;
  }
  for (int off = 32; off; off >>= 1) acc += __shfl_down(acc, off);
  if (lane == 0) demod[wid] = rsqrtf(acc + 1e-8f);
}

// ---------------- K2b: weight pre-transform to MFMA fragment layout ----------------
// layout: [tap(9)][cb(2)][kb(8)][kc(4)][co_row(128)][j(8)]   (hi / lo arrays)
__global__ __launch_bounds__(256) void k_prep_w(const float* __restrict__ W,
                                                ushort_t* __restrict__ Wth,
                                                ushort_t* __restrict__ Wtl) {
  int idx = blockIdx.x * 256 + threadIdx.x;
  if (idx >= 589824) return;
  int j  = idx & 7;
  int co = (idx >> 3) & 127;
  int kc = (idx >> 10) & 3;
  int kb = (idx >> 12) & 7;
  int cb = (idx >> 15) & 1;
  int t  = idx >> 16;
  int ci  = kb * 32 + kc * 8 + j;
  int cog = cb * 128 + co;
  float v = W[(cog * CIN_ + ci) * 9 + t];
  ushort_t h = f2bf_(v);
  Wth[idx] = h;
  Wtl[idx] = f2bf_(v - bf2f_(h));
}

// ---------------- K2c: X pre-transform ----------------
// Xt layout: [b(4)][part(2)][py(128)][px(128)][ci(256)] bf16 (part0=hi, part1=lo)
__global__ __launch_bounds__(256) void k_prep_x(const float* __restrict__ input,
                                                const float* __restrict__ s,
                                                ushort_t* __restrict__ Xt,
                                                float* __restrict__ zp) {
  int b = blockIdx.z, cb = blockIdx.y, px0 = blockIdx.x * 64;
  int tid = threadIdx.x;
  __shared__ float T[64 * 131];
  __shared__ float sSh[128];
  if (tid < 128) sSh[tid] = s[b * 256 + cb * 128 + tid];
  if (blockIdx.x == 0 && blockIdx.y == 0 && blockIdx.z == 0 && tid < 4)
    zp[tid] = 0.f;                       // 16B zero page for OOB gll lanes
  __syncthreads();
  const float* inb = input + (size_t)(b * 256 + cb * 128) * HW_ + px0;
#pragma unroll
  for (int r2 = 0; r2 < 32; ++r2) {
    int idx = r2 * 256 + tid;
    int ci = idx >> 6, p = idx & 63;
    T[p * 131 + ci] = inb[(size_t)ci * HW_ + p] * sSh[ci];
  }
  __syncthreads();
  ushort_t* xb = Xt + (size_t)b * 2 * HW_ * 256 + cb * 128;
#pragma unroll
  for (int r2 = 0; r2 < 32; ++r2) {
    int u = r2 * 256 + tid;
    int cp = u & 63, part = (u >> 6) & 1, p = u >> 7;
    float v0 = T[p * 131 + 2 * cp], v1 = T[p * 131 + 2 * cp + 1];
    ushort_t h0 = f2bf_(v0), h1 = f2bf_(v1);
    ushort_t e0, e1;
    if (part == 0) { e0 = h0; e1 = h1; }
    else { e0 = f2bf_(v0 - bf2f_(h0)); e1 = f2bf_(v1 - bf2f_(h1)); }
    unsigned pk = (unsigned)e0 | ((unsigned)e1 << 16);
    *(unsigned*)(xb + ((size_t)part * HW_ + px0 + p) * 256 + cp * 2) = pk;
  }
}

// ---------------- K3: modulated conv via MFMA (bf16 split-3) ----------------
// block: 128co x (10y x 16x); X staged via global_load_lds (dbuf, 1 barrier/kb);
// W fragments direct from L2; B-fragment reused across the 3 ky taps.
// Per kb: kx0 W-loads FIRST, then the 7 glls (pinned) -> the first MFMA's W-wait
// does not serialize behind the HBM stage (vmcnt retires in issue order).
#define XCELLS 864           // 4kc * 216 cells (12hy*18hx)
#define XUNITS 1728          // 2 parts * 864
#define XROUNDS 7
#define XBUFU  1792          // padded to 7*256 units

__global__ __launch_bounds__(256, 2) void k_conv_mfma(
    const ushort_t* __restrict__ Xt, const ushort_t* __restrict__ Wth,
    const ushort_t* __restrict__ Wtl, const float* __restrict__ demod,
    const float* __restrict__ bias, const ushort_t* __restrict__ zpg,
    float* __restrict__ out1) {
  const int tid = threadIdx.x;
  const int b = blockIdx.z >> 1, cb = blockIdx.z & 1;
  const int y0 = blockIdx.y * 10, x0 = blockIdx.x * 16;
  const int lane = tid & 63, lr = lane & 15, kcc = lane >> 4;
  const int w = tid >> 6;

  __shared__ __align__(16) ushort_t XL[2][XBUFU * 8];   // 2 x 28 KB

  f32x4 acc[2][10];
#pragma unroll
  for (int i = 0; i < 2; ++i)
#pragma unroll
    for (int jj = 0; jj < 10; ++jj) acc[i][jj] = (f32x4)0.f;

  // precompute per-round gather pointers (kb-independent)
  const ushort_t* gsrc[XROUNDS];
  bool okr[XROUNDS];
#pragma unroll
  for (int r = 0; r < XROUNDS; ++r) {
    int u = r * 256 + tid;
    const ushort_t* p = zpg;
    bool ok = false;
    if (u < XUNITS) {
      int part = (u >= XCELLS) ? 1 : 0;
      int v = u - part * XCELLS;
      int kc = v / 216, cell = v - kc * 216;
      int hy = cell / 18, hx = cell - hy * 18;
      int iy = y0 + hy - 2, ix = x0 + hx - 2;
      if ((unsigned)iy < 128u && (unsigned)ix < 128u) {
        p = Xt + (((size_t)(b * 2 + part) * HW_ + iy * W_ + ix) << 8) + kc * 8;
        ok = true;
      }
    }
    gsrc[r] = p; okr[r] = ok;
  }

  auto stage = [&](int kb, int bufsel) {
    ushort_t* lb = &XL[bufsel][(size_t)tid * 8];
#pragma unroll
    for (int r = 0; r < XROUNDS; ++r) {
      const ushort_t* g = okr[r] ? gsrc[r] + kb * 32 : zpg;
      gll16(g, lb + r * 2048);
    }
  };

  stage(0, 0);
  __syncthreads();                         // drains vmcnt -> buf0 ready

  for (int kb = 0; kb < 8; ++kb) {
    const ushort_t* Xc = &XL[kb & 1][0];
    const int wbo = cb * 32768 + kb * 4096 + kcc * 1024 + (w * 32 + lr) * 8;
#pragma unroll
    for (int kx = 0; kx < 3; ++kx) {
      short8 ah[3][2], al[3][2];
#pragma unroll
      for (int ky = 0; ky < 3; ++ky) {
        const int t = ky * 3 + kx;
        const ushort_t* wh = Wth + wbo + t * 65536;
        const ushort_t* wl = Wtl + wbo + t * 65536;
        ah[ky][0] = *(const short8*)wh;
        ah[ky][1] = *(const short8*)(wh + 128);
        al[ky][0] = *(const short8*)wl;
        al[ky][1] = *(const short8*)(wl + 128);
      }
      if (kx == 0) {
        // keep W loads older than the glls in the vmcnt queue
        __builtin_amdgcn_sched_barrier(0);
        if (kb < 7) stage(kb + 1, (kb & 1) ^ 1);   // async into other buffer
      }
#pragma unroll
      for (int r = 0; r < 12; ++r) {
        const int c16 = (kcc * 216 + r * 18 + lr + kx) * 8;
        short8 bh = *(const short8*)&Xc[c16];
        short8 bl = *(const short8*)&Xc[c16 + 6912];
#pragma unroll
        for (int ky = 0; ky < 3; ++ky) {
          const int bn = r - ky;
          if (bn >= 0 && bn < 10) {
            acc[0][bn] = __builtin_amdgcn_mfma_f32_16x16x32_bf16(ah[ky][0], bh, acc[0][bn], 0, 0, 0);
            acc[0][bn] = __builtin_amdgcn_mfma_f32_16x16x32_bf16(ah[ky][0], bl, acc[0][bn], 0, 0, 0);
            acc[0][bn] = __builtin_amdgcn_mfma_f32_16x16x32_bf16(al[ky][0], bh, acc[0][bn], 0, 0, 0);
            acc[1][bn] = __builtin_amdgcn_mfma_f32_16x16x32_bf16(ah[ky][1], bh, acc[1][bn], 0, 0, 0);
            acc[1][bn] = __builtin_amdgcn_mfma_f32_16x16x32_bf16(ah[ky][1], bl, acc[1][bn], 0, 0, 0);
            acc[1][bn] = __builtin_amdgcn_mfma_f32_16x16x32_bf16(al[ky][1], bh, acc[1][bn], 0, 0, 0);
          }
        }
      }
    }
    if (kb < 7) __syncthreads();           // all waves done with buf; next buf ready
  }

  // epilogue: * demod + bias
#pragma unroll
  for (int am = 0; am < 2; ++am) {
#pragma unroll
    for (int r = 0; r < 4; ++r) {
      int cog = cb * 128 + w * 32 + am * 16 + kcc * 4 + r;
      float dm = demod[b * 256 + cog];
      float bv = bias[cog];
      int ox = x0 + lr;
      if (ox < HO_) {
#pragma unroll
        for (int bn = 0; bn < 10; ++bn) {
          int oy = y0 + bn;
          out1[((b * 256 + cog) * HO_ + oy) * HO_ + ox] = acc[am][bn][r] * dm + bv;
        }
      }
    }
  }
}

// ---------------- K4: fused FIR up(2x) -> lrelu -> FIR down(2x) ----------------
#define TS 26
#define XR 36
#define UR 62

__global__ __launch_bounds__(256) void k_fir(const float* __restrict__ src,
                                             const float* __restrict__ upf,
                                             const float* __restrict__ dnf,
                                             float* __restrict__ dst) {
  int plane = blockIdx.z;
  int y0 = blockIdx.y * TS, x0 = blockIdx.x * TS;
  int tid = threadIdx.x;

  __shared__ float buf1[UR * 63];
  __shared__ float buf2[UR * 37];
  __shared__ float fu[NT_], fd[NT_];
  if (tid < NT_) { fu[tid] = upf[tid] * 2.f; fd[tid] = dnf[tid]; }

  const float* sp = src + (size_t)plane * HO_ * HO_;
  for (int idx = tid; idx < XR * XR; idx += 256) {
    int r = idx / XR, c = idx % XR;
    int gy = y0 - 5 + r, gx = x0 - 5 + c;
    float v = 0.f;
    if (gy >= 0 && gy < HO_ && gx >= 0 && gx < HO_) v = sp[gy * HO_ + gx];
    buf1[r * 37 + c] = v;
  }
  __syncthreads();

  for (int idx = tid; idx < UR * XR; idx += 256) {
    int u = idx / XR, c = idx % XR;
    int ug = 2 * y0 - 5 + u;
    float a = 0.f;
    if (ug >= 0 && ug < HU_) {
      int base, toff;
      if (ug & 1) { base = (ug - 5) >> 1; toff = 1; }
      else        { base = (ug >> 1) - 3; toff = 0; }
      int lr2 = base - (y0 - 5);
#pragma unroll
      for (int j = 0; j < 6; ++j) a += fu[2 * j + toff] * buf1[(lr2 + j) * 37 + c];
    }
    buf2[u * 37 + c] = a;
  }
  __syncthreads();

  for (int idx = tid; idx < UR * UR; idx += 256) {
    int u = idx / UR, v = idx % UR;
    int ug = 2 * y0 - 5 + u;
    int vg = 2 * x0 - 5 + v;
    float a = 0.f;
    if (ug >= 0 && ug < HU_ && vg >= 0 && vg < HU_) {
      int base, toff;
      if (vg & 1) { base = (vg - 5) >> 1; toff = 1; }
      else        { base = (vg >> 1) - 3; toff = 0; }
      int lc = base - (x0 - 5);
#pragma unroll
      for (int j = 0; j < 6; ++j) a += fu[2 * j + toff] * buf2[u * 37 + lc + j];
      a = (a >= 0.f ? a : 0.2f * a) * 1.41421356237309515f;
      a = fminf(fmaxf(a, -256.f), 256.f);
    }
    buf1[u * 63 + v] = a;
  }
  __syncthreads();

  for (int idx = tid; idx < TS * UR; idx += 256) {
    int y = idx / UR, v = idx % UR;
    float a = 0.f;
#pragma unroll
    for (int t = 0; t < NT_; ++t) a += fd[t] * buf1[(2 * y + t) * 63 + v];
    buf2[y * 63 + v] = a;
  }
  __syncthreads();

  float* dp = dst + (size_t)plane * HO_ * HO_;
  for (int idx = tid; idx < TS * TS; idx += 256) {
    int y = idx / TS, x = idx % TS;
    float a = 0.f;
#pragma unroll
    for (int t = 0; t < NT_; ++t) a += fd[t] * buf2[y * 63 + 2 * x + t];
    dp[(y0 + y) * HO_ + (x0 + x)] = a;
  }
}

// ---------------- launch ----------------
extern "C" void kernel_launch(void* const* d_in, const int* in_sizes, int n_in,
                              void* d_out, int out_size, void* d_ws, size_t ws_size,
                              hipStream_t stream) {
  (void)in_sizes; (void)n_in; (void)out_size; (void)ws_size;
  const float* input  = (const float*)d_in[0];
  const float* style  = (const float*)d_in[1];
  const float* weight = (const float*)d_in[2];
  const float* mw     = (const float*)d_in[3];
  const float* mb     = (const float*)d_in[4];
  const float* bias   = (const float*)d_in[5];
  const float* upf    = (const float*)d_in[6];
  const float* dnf    = (const float*)d_in[7];
  float* out = (float*)d_out;

  float* out1   = (float*)d_ws;                               // 69.22 MB
  float* s      = out1 + (size_t)B_ * COUT_ * HO_ * HO_;      // [4][256]
  float* demod  = s + B_ * CIN_;                              // [4][256]
  ushort_t* Wth = (ushort_t*)(demod + B_ * COUT_);            // 1.18 MB
  ushort_t* Wtl = Wth + 589824;                               // 1.18 MB
  float*    zp  = (float*)(Wtl + 589824);                     // 16 B zero page
  ushort_t* Xt  = (ushort_t*)(zp + 4);                        // 64 MB

  k_mod   <<<256, 256, 0, stream>>>(style, mw, mb, s);
  k_prep_x<<<dim3(256, 2, B_), 256, 0, stream>>>(input, s, Xt, zp);
  k_demod <<<256, 256, 0, stream>>>(weight, s, demod);
  k_prep_w<<<2304, 256, 0, stream>>>(weight, Wth, Wtl);
  k_conv_mfma<<<dim3(9, 13, 8), 256, 0, stream>>>(Xt, Wth, Wtl, demod, bias,
                                                  (const ushort_t*)zp, out1);
  k_fir   <<<dim3(5, 5, B_ * COUT_), 256, 0, stream>>>(out1, upf, dnf, out);
}

// Round 9
// 439.407 us; speedup vs baseline: 2.4627x; 1.0526x over previous
//
#include <hip/hip_runtime.h>
#include <hip/hip_bf16.h>
#include <math.h>

#define B_    4
#define CIN_  256
#define COUT_ 256
#define H_    128
#define W_    128
#define HW_   16384
#define SD_   512
#define HO_   130
#define HU_   260
#define NT_   12

typedef unsigned short ushort_t;
typedef __attribute__((ext_vector_type(8))) short short8;
typedef __attribute__((ext_vector_type(4))) float f32x4;

__device__ inline ushort_t f2bf_(float v) {
  union { float f; unsigned u; } x; x.f = v;
  unsigned r = x.u + 0x7fffu + ((x.u >> 16) & 1u);
  return (ushort_t)(r >> 16);
}
__device__ inline float bf2f_(ushort_t h) {
  union { unsigned u; float f; } x; x.u = ((unsigned)h) << 16;
  return x.f;
}
__device__ inline void gll16(const ushort_t* g, ushort_t* l) {
  __builtin_amdgcn_global_load_lds(
      (const __attribute__((address_space(1))) unsigned int*)g,
      (__attribute__((address_space(3))) unsigned int*)l, 16, 0, 0);
}

// ---------------- K1: modulation s[b][cin] ----------------
__global__ __launch_bounds__(256) void k_mod(const float* __restrict__ style,
                                             const float* __restrict__ mw,
                                             const float* __restrict__ mb,
                                             float* __restrict__ s) {
  int wid  = (blockIdx.x * blockDim.x + threadIdx.x) >> 6;
  int lane = threadIdx.x & 63;
  int b = wid >> 8, ci = wid & 255;
  const float* st = style + b * SD_;
  const float* w  = mw + ci * SD_;
  float acc = 0.f;
  for (int k = lane; k < SD_; k += 64) acc += st[k] * w[k];
  for (int off = 32; off; off >>= 1) acc += __shfl_down(acc, off);
  if (lane == 0) s[wid] = acc * 0.044194173824159216f + mb[ci];
}

// ---------------- K2: demod[b][cout] ----------------
__global__ __launch_bounds__(256) void k_demod(const float* __restrict__ weight,
                                               const float* __restrict__ s,
                                               float* __restrict__ demod) {
  int wid  = (blockIdx.x * blockDim.x + threadIdx.x) >> 6;
  int lane = threadIdx.x & 63;
  int b = wid >> 8, co = wid & 255;
  const float* wrow = weight + co * CIN_ * 9;
  const float* sb   = s + b * CIN_;
  float acc = 0.f;
  for (int e = lane; e < CIN_ * 9; e += 64) {
    float p = wrow[e] * sb[e / 9];
    acc += p * p;
  }
  for (int off = 32; off; off >>= 1) acc += __shfl_down(acc, off);
  if (lane == 0) demod[wid] = rsqrtf(acc + 1e-8f);
}

// ---------------- K2b: weight pre-transform to MFMA fragment layout ----------------
__global__ __launch_bounds__(256) void k_prep_w(const float* __restrict__ W,
                                                ushort_t* __restrict__ Wth,
                                                ushort_t* __restrict__ Wtl) {
  int idx = blockIdx.x * 256 + threadIdx.x;
  if (idx >= 589824) return;
  int j  = idx & 7;
  int co = (idx >> 3) & 127;
  int kc = (idx >> 10) & 3;
  int kb = (idx >> 12) & 7;
  int cb = (idx >> 15) & 1;
  int t  = idx >> 16;
  int ci  = kb * 32 + kc * 8 + j;
  int cog = cb * 128 + co;
  float v = W[(cog * CIN_ + ci) * 9 + t];
  ushort_t h = f2bf_(v);
  Wth[idx] = h;
  Wtl[idx] = f2bf_(v - bf2f_(h));
}

// ---------------- K2c: X pre-transform ----------------
__global__ __launch_bounds__(256) void k_prep_x(const float* __restrict__ input,
                                                const float* __restrict__ s,
                                                ushort_t* __restrict__ Xt,
                                                float* __restrict__ zp) {
  int b = blockIdx.z, cb = blockIdx.y, px0 = blockIdx.x * 64;
  int tid = threadIdx.x;
  __shared__ float T[64 * 131];
  __shared__ float sSh[128];
  if (tid < 128) sSh[tid] = s[b * 256 + cb * 128 + tid];
  if (blockIdx.x == 0 && blockIdx.y == 0 && blockIdx.z == 0 && tid < 4)
    zp[tid] = 0.f;
  __syncthreads();
  const float* inb = input + (size_t)(b * 256 + cb * 128) * HW_ + px0;
#pragma unroll
  for (int r2 = 0; r2 < 32; ++r2) {
    int idx = r2 * 256 + tid;
    int ci = idx >> 6, p = idx & 63;
    T[p * 131 + ci] = inb[(size_t)ci * HW_ + p] * sSh[ci];
  }
  __syncthreads();
  ushort_t* xb = Xt + (size_t)b * 2 * HW_ * 256 + cb * 128;
#pragma unroll
  for (int r2 = 0; r2 < 32; ++r2) {
    int u = r2 * 256 + tid;
    int cp = u & 63, part = (u >> 6) & 1, p = u >> 7;
    float v0 = T[p * 131 + 2 * cp], v1 = T[p * 131 + 2 * cp + 1];
    ushort_t h0 = f2bf_(v0), h1 = f2bf_(v1);
    ushort_t e0, e1;
    if (part == 0) { e0 = h0; e1 = h1; }
    else { e0 = f2bf_(v0 - bf2f_(h0)); e1 = f2bf_(v1 - bf2f_(h1)); }
    unsigned pk = (unsigned)e0 | ((unsigned)e1 << 16);
    *(unsigned*)(xb + ((size_t)part * HW_ + px0 + p) * 256 + cp * 2) = pk;
  }
}

// ---------------- K3: modulated conv via MFMA (unchanged) ----------------
#define XCELLS 864
#define XUNITS 1728
#define XROUNDS 7
#define XBUFU  1792

__global__ __launch_bounds__(256, 2) void k_conv_mfma(
    const ushort_t* __restrict__ Xt, const ushort_t* __restrict__ Wth,
    const ushort_t* __restrict__ Wtl, const float* __restrict__ demod,
    const float* __restrict__ bias, const ushort_t* __restrict__ zpg,
    float* __restrict__ out1) {
  const int tid = threadIdx.x;
  const int b = blockIdx.z >> 1, cb = blockIdx.z & 1;
  const int y0 = blockIdx.y * 10, x0 = blockIdx.x * 16;
  const int lane = tid & 63, lr = lane & 15, kcc = lane >> 4;
  const int w = tid >> 6;

  __shared__ __align__(16) ushort_t XL[2][XBUFU * 8];

  f32x4 acc[2][10];
#pragma unroll
  for (int i = 0; i < 2; ++i)
#pragma unroll
    for (int jj = 0; jj < 10; ++jj) acc[i][jj] = (f32x4)0.f;

  const ushort_t* gsrc[XROUNDS];
  bool okr[XROUNDS];
#pragma unroll
  for (int r = 0; r < XROUNDS; ++r) {
    int u = r * 256 + tid;
    const ushort_t* p = zpg;
    bool ok = false;
    if (u < XUNITS) {
      int part = (u >= XCELLS) ? 1 : 0;
      int v = u - part * XCELLS;
      int kc = v / 216, cell = v - kc * 216;
      int hy = cell / 18, hx = cell - hy * 18;
      int iy = y0 + hy - 2, ix = x0 + hx - 2;
      if ((unsigned)iy < 128u && (unsigned)ix < 128u) {
        p = Xt + (((size_t)(b * 2 + part) * HW_ + iy * W_ + ix) << 8) + kc * 8;
        ok = true;
      }
    }
    gsrc[r] = p; okr[r] = ok;
  }

  auto stage = [&](int kb, int bufsel) {
    ushort_t* lb = &XL[bufsel][(size_t)tid * 8];
#pragma unroll
    for (int r = 0; r < XROUNDS; ++r) {
      const ushort_t* g = okr[r] ? gsrc[r] + kb * 32 : zpg;
      gll16(g, lb + r * 2048);
    }
  };

  stage(0, 0);
  __syncthreads();

  for (int kb = 0; kb < 8; ++kb) {
    const ushort_t* Xc = &XL[kb & 1][0];
    const int wbo = cb * 32768 + kb * 4096 + kcc * 1024 + (w * 32 + lr) * 8;
#pragma unroll
    for (int kx = 0; kx < 3; ++kx) {
      short8 ah[3][2], al[3][2];
#pragma unroll
      for (int ky = 0; ky < 3; ++ky) {
        const int t = ky * 3 + kx;
        const ushort_t* wh = Wth + wbo + t * 65536;
        const ushort_t* wl = Wtl + wbo + t * 65536;
        ah[ky][0] = *(const short8*)wh;
        ah[ky][1] = *(const short8*)(wh + 128);
        al[ky][0] = *(const short8*)wl;
        al[ky][1] = *(const short8*)(wl + 128);
      }
      if (kx == 0) {
        __builtin_amdgcn_sched_barrier(0);
        if (kb < 7) stage(kb + 1, (kb & 1) ^ 1);
      }
#pragma unroll
      for (int r = 0; r < 12; ++r) {
        const int c16 = (kcc * 216 + r * 18 + lr + kx) * 8;
        short8 bh = *(const short8*)&Xc[c16];
        short8 bl = *(const short8*)&Xc[c16 + 6912];
#pragma unroll
        for (int ky = 0; ky < 3; ++ky) {
          const int bn = r - ky;
          if (bn >= 0 && bn < 10) {
            acc[0][bn] = __builtin_amdgcn_mfma_f32_16x16x32_bf16(ah[ky][0], bh, acc[0][bn], 0, 0, 0);
            acc[0][bn] = __builtin_amdgcn_mfma_f32_16x16x32_bf16(ah[ky][0], bl, acc[0][bn], 0, 0, 0);
            acc[0][bn] = __builtin_amdgcn_mfma_f32_16x16x32_bf16(al[ky][0], bh, acc[0][bn], 0, 0, 0);
            acc[1][bn] = __builtin_amdgcn_mfma_f32_16x16x32_bf16(ah[ky][1], bh, acc[1][bn], 0, 0, 0);
            acc[1][bn] = __builtin_amdgcn_mfma_f32_16x16x32_bf16(ah[ky][1], bl, acc[1][bn], 0, 0, 0);
            acc[1][bn] = __builtin_amdgcn_mfma_f32_16x16x32_bf16(al[ky][1], bh, acc[1][bn], 0, 0, 0);
          }
        }
      }
    }
    if (kb < 7) __syncthreads();
  }

#pragma unroll
  for (int am = 0; am < 2; ++am) {
#pragma unroll
    for (int r = 0; r < 4; ++r) {
      int cog = cb * 128 + w * 32 + am * 16 + kcc * 4 + r;
      float dm = demod[b * 256 + cog];
      float bv = bias[cog];
      int ox = x0 + lr;
      if (ox < HO_) {
#pragma unroll
        for (int bn = 0; bn < 10; ++bn) {
          int oy = y0 + bn;
          out1[((b * 256 + cog) * HO_ + oy) * HO_ + ox] = acc[am][bn][r] * dm + bv;
        }
      }
    }
  }
}

// ---------------- K4: fused FIR, full-width row bands ----------------
// FIX r8: uh=1 sliding-window refill row was lr+7, must be lr+6 (off-by-one).
__global__ __launch_bounds__(256) void k_fir(const float* __restrict__ src,
                                             const float* __restrict__ upf,
                                             const float* __restrict__ dnf,
                                             float* __restrict__ dst) {
  const int plane = blockIdx.y;
  const int y0 = blockIdx.x * 8;
  const int tid = threadIdx.x;

  __shared__ __align__(16) float I1[26 * 141];   // cols offset +3, zero-padded
  __shared__ __align__(16) float I2[26 * 266];
  __shared__ __align__(16) float SD[18 * 132];   // S (18x132) then D (8x272)

  float fe[6], fo[6], fdt[12];
#pragma unroll
  for (int j = 0; j < 6; ++j) { fe[j] = upf[2 * j] * 2.f; fo[j] = upf[2 * j + 1] * 2.f; }
#pragma unroll
  for (int t = 0; t < NT_; ++t) fdt[t] = dnf[t];

  // ---- P0: stage src rows [y0-5, y0+13) ----
  const float* sp = src + (size_t)plane * (HO_ * HO_);
#pragma unroll
  for (int k = 0; k < 10; ++k) {
    int idx = tid + k * 256;
    if (idx < 18 * 132) {
      int r = idx / 132, cc = idx - 132 * r;
      int gy = y0 - 5 + r;
      float v = 0.f;
      if ((unsigned)gy < (unsigned)HO_ && cc < HO_) v = sp[gy * HO_ + cc];
      SD[idx] = v;
    }
  }
  __syncthreads();

  // ---- P1: vertical up-FIR -> I1[u][c+3], u in [0,26); zero if ug outside [0,260) ----
  {
    int c = tid & 127, uh = tid >> 7;
    float wv[6];
    if (uh == 0) {
      // evens u=2*lr (ug odd, taps fo), lr 0..6, rows lr..lr+5
#pragma unroll
      for (int j = 0; j < 6; ++j) wv[j] = SD[j * 132 + c];
#pragma unroll
      for (int lr = 0; lr < 7; ++lr) {
        float a = fo[0]*wv[0] + fo[1]*wv[1] + fo[2]*wv[2] + fo[3]*wv[3] + fo[4]*wv[4] + fo[5]*wv[5];
        int ugl = 2 * y0 - 5 + 2 * lr;
        I1[(2 * lr) * 141 + c + 3] = ((unsigned)ugl < (unsigned)HU_) ? a : 0.f;
        if (lr < 6) {
#pragma unroll
          for (int j = 0; j < 5; ++j) wv[j] = wv[j + 1];
          wv[5] = SD[(lr + 6) * 132 + c];
        }
      }
      // odds u=2*lr+1 (ug even, taps fe), lr 0..5
#pragma unroll
      for (int j = 0; j < 6; ++j) wv[j] = SD[j * 132 + c];
#pragma unroll
      for (int lr = 0; lr < 6; ++lr) {
        float a = fe[0]*wv[0] + fe[1]*wv[1] + fe[2]*wv[2] + fe[3]*wv[3] + fe[4]*wv[4] + fe[5]*wv[5];
        int ugl = 2 * y0 - 4 + 2 * lr;
        I1[(2 * lr + 1) * 141 + c + 3] = ((unsigned)ugl < (unsigned)HU_) ? a : 0.f;
        if (lr < 5) {
#pragma unroll
          for (int j = 0; j < 5; ++j) wv[j] = wv[j + 1];
          wv[5] = SD[(lr + 6) * 132 + c];
        }
      }
    } else {
      // odds u=2*lr+1 (taps fe), lr 6..12, rows lr..lr+5
#pragma unroll
      for (int j = 0; j < 6; ++j) wv[j] = SD[(6 + j) * 132 + c];
#pragma unroll
      for (int lr = 6; lr < 13; ++lr) {
        float a = fe[0]*wv[0] + fe[1]*wv[1] + fe[2]*wv[2] + fe[3]*wv[3] + fe[4]*wv[4] + fe[5]*wv[5];
        int ugl = 2 * y0 - 4 + 2 * lr;
        I1[(2 * lr + 1) * 141 + c + 3] = ((unsigned)ugl < (unsigned)HU_) ? a : 0.f;
        if (lr < 12) {
#pragma unroll
          for (int j = 0; j < 5; ++j) wv[j] = wv[j + 1];
          wv[5] = SD[(lr + 6) * 132 + c];   // FIX r8 (was lr+7)
        }
      }
      // evens u=2*lr (taps fo), lr 7..12, rows lr..lr+5
#pragma unroll
      for (int j = 0; j < 6; ++j) wv[j] = SD[(7 + j) * 132 + c];
#pragma unroll
      for (int lr = 7; lr < 13; ++lr) {
        float a = fo[0]*wv[0] + fo[1]*wv[1] + fo[2]*wv[2] + fo[3]*wv[3] + fo[4]*wv[4] + fo[5]*wv[5];
        int ugl = 2 * y0 - 5 + 2 * lr;
        I1[(2 * lr) * 141 + c + 3] = ((unsigned)ugl < (unsigned)HU_) ? a : 0.f;
        if (lr < 12) {
#pragma unroll
          for (int j = 0; j < 5; ++j) wv[j] = wv[j + 1];
          wv[5] = SD[(lr + 6) * 132 + c];   // FIX r8 (was lr+7)
        }
      }
    }
    // extra columns c=128,129 (52 tasks)
    if (tid >= 200 && tid < 252) {
      int t2 = tid - 200;
      int c2 = 128 + (t2 & 1), u2 = t2 >> 1;
      float a = 0.f;
      if ((u2 & 1) == 0) {
        int lr = u2 >> 1;
#pragma unroll
        for (int j = 0; j < 6; ++j) a += fo[j] * SD[(lr + j) * 132 + c2];
      } else {
        int lr = (u2 - 1) >> 1;
#pragma unroll
        for (int j = 0; j < 6; ++j) a += fe[j] * SD[(lr + j) * 132 + c2];
      }
      int ugl = 2 * y0 - 5 + u2;
      I1[u2 * 141 + c2 + 3] = ((unsigned)ugl < (unsigned)HU_) ? a : 0.f;
    }
    // zero-fill I1 edge cols {0,1,2} U {133..140}
    for (int zz = tid; zz < 286; zz += 256) {
      int r = zz / 11, j = zz - 11 * r;
      int col = (j < 3) ? j : (130 + j);
      I1[r * 141 + col] = 0.f;
    }
  }
  __syncthreads();

  // ---- P2: horizontal up-FIR + lrelu + clamp -> I2[u][v]  (flat 26x33 tasks) ----
  for (int idx = tid; idx < 26 * 33; idx += 256) {
    int u = idx / 33, s = idx - 33 * u;
    if (s < 32) {
      int c0 = 4 * s;
      float win[10];
#pragma unroll
      for (int k = 0; k < 10; ++k) win[k] = I1[u * 141 + c0 + k];
      float o[8];
#pragma unroll
      for (int e = 0; e < 4; ++e) {
        o[2*e]   = fe[0]*win[e]   + fe[1]*win[e+1] + fe[2]*win[e+2] + fe[3]*win[e+3] + fe[4]*win[e+4] + fe[5]*win[e+5];
        o[2*e+1] = fo[0]*win[e+1] + fo[1]*win[e+2] + fo[2]*win[e+3] + fo[3]*win[e+4] + fo[4]*win[e+5] + fo[5]*win[e+6];
      }
#pragma unroll
      for (int e = 0; e < 8; ++e) {
        float a = o[e];
        a = (a >= 0.f ? a : 0.2f * a) * 1.41421356237309515f;
        a = fminf(fmaxf(a, -256.f), 256.f);
        I2[u * 266 + 8 * s + e] = a;
      }
    } else {
      float wr[8];
#pragma unroll
      for (int k = 0; k < 8; ++k) wr[k] = I1[u * 141 + 128 + k];
      float q[4];
      q[0] = fe[0]*wr[0] + fe[1]*wr[1] + fe[2]*wr[2] + fe[3]*wr[3] + fe[4]*wr[4] + fe[5]*wr[5];
      q[1] = fo[0]*wr[1] + fo[1]*wr[2] + fo[2]*wr[3] + fo[3]*wr[4] + fo[4]*wr[5] + fo[5]*wr[6];
      q[2] = fe[0]*wr[1] + fe[1]*wr[2] + fe[2]*wr[3] + fe[3]*wr[4] + fe[4]*wr[5] + fe[5]*wr[6];
      q[3] = fo[0]*wr[2] + fo[1]*wr[3] + fo[2]*wr[4] + fo[3]*wr[5] + fo[4]*wr[6] + fo[5]*wr[7];
#pragma unroll
      for (int e = 0; e < 4; ++e) {
        float a = q[e];
        a = (a >= 0.f ? a : 0.2f * a) * 1.41421356237309515f;
        a = fminf(fmaxf(a, -256.f), 256.f);
        I2[u * 266 + 256 + e] = a;
      }
    }
  }
  __syncthreads();

  // ---- P3: vertical down-FIR -> D[y][v+5] (D overlays S) ----
  {
    if (tid < 96) {
      int r = tid / 12, j = tid - 12 * r;
      int col = (j < 5) ? j : (260 + j);
      SD[r * 272 + col] = 0.f;
    }
    auto p3col = [&](int v) {
      float wn[12];
#pragma unroll
      for (int t = 0; t < 12; ++t) wn[t] = I2[t * 266 + v];
#pragma unroll
      for (int y = 0; y < 8; ++y) {
        float a = 0.f;
#pragma unroll
        for (int t = 0; t < 12; ++t) a += fdt[t] * wn[t];
        SD[y * 272 + v + 5] = a;
        if (y < 7) {
#pragma unroll
          for (int t = 0; t < 10; ++t) wn[t] = wn[t + 2];
          wn[10] = I2[(2 * y + 12) * 266 + v];
          wn[11] = I2[(2 * y + 13) * 266 + v];
        }
      }
    };
    p3col(tid);
    if (tid < 4) p3col(256 + tid);
  }
  __syncthreads();

  // ---- P4: horizontal down-FIR -> global ----
  if (tid < 208) {
    int row = tid / 26, s4 = tid - 26 * row;
    int gy = y0 + row;
    if (gy < HO_) {
      float wn[20];
#pragma unroll
      for (int k = 0; k < 20; ++k) wn[k] = SD[row * 272 + 10 * s4 + k];
      float* dp = dst + (size_t)plane * (HO_ * HO_) + gy * HO_ + 5 * s4;
#pragma unroll
      for (int q = 0; q < 5; ++q) {
        float a = 0.f;
#pragma unroll
        for (int t = 0; t < 12; ++t) a += fdt[t] * wn[2 * q + t];
        dp[q] = a;
      }
    }
  }
}

// ---------------- launch ----------------
extern "C" void kernel_launch(void* const* d_in, const int* in_sizes, int n_in,
                              void* d_out, int out_size, void* d_ws, size_t ws_size,
                              hipStream_t stream) {
  (void)in_sizes; (void)n_in; (void)out_size; (void)ws_size;
  const float* input  = (const float*)d_in[0];
  const float* style  = (const float*)d_in[1];
  const float* weight = (const float*)d_in[2];
  const float* mw     = (const float*)d_in[3];
  const float* mb     = (const float*)d_in[4];
  const float* bias   = (const float*)d_in[5];
  const float* upf    = (const float*)d_in[6];
  const float* dnf    = (const float*)d_in[7];
  float* out = (float*)d_out;

  float* out1   = (float*)d_ws;                               // 69.22 MB
  float* s      = out1 + (size_t)B_ * COUT_ * HO_ * HO_;      // [4][256]
  float* demod  = s + B_ * CIN_;                              // [4][256]
  ushort_t* Wth = (ushort_t*)(demod + B_ * COUT_);            // 1.18 MB
  ushort_t* Wtl = Wth + 589824;                               // 1.18 MB
  float*    zp  = (float*)(Wtl + 589824);                     // 16 B zero page
  ushort_t* Xt  = (ushort_t*)(zp + 4);                        // 64 MB

  k_mod   <<<256, 256, 0, stream>>>(style, mw, mb, s);
  k_prep_x<<<dim3(256, 2, B_), 256, 0, stream>>>(input, s, Xt, zp);
  k_demod <<<256, 256, 0, stream>>>(weight, s, demod);
  k_prep_w<<<2304, 256, 0, stream>>>(weight, Wth, Wtl);
  k_conv_mfma<<<dim3(9, 13, 8), 256, 0, stream>>>(Xt, Wth, Wtl, demod, bias,
                                                  (const ushort_t*)zp, out1);
  k_fir   <<<dim3(17, 1024), 256, 0, stream>>>(out1, upf, dnf, out);
}